// Round 15
// baseline (15231.973 us; speedup 1.0000x reference)
//
#include <hip/hip_runtime.h>

typedef short s16x8 __attribute__((ext_vector_type(8)));
typedef unsigned short us8 __attribute__((ext_vector_type(8)));
typedef float f32x4 __attribute__((ext_vector_type(4)));

#define TC 16   // time-chunk length

// ---------- helpers ----------
__device__ __forceinline__ ushort f2bf(float f) {
  union { float f; unsigned u; } v; v.f = f;
  unsigned u = v.u;
  u += 0x7fffu + ((u >> 16) & 1u);
  return (ushort)(u >> 16);
}
__device__ __forceinline__ float bf2f(ushort h) {
  union { unsigned u; float f; } v; v.u = ((unsigned)h) << 16; return v.f;
}
__device__ __forceinline__ float sigm(float x) { return 1.f / (1.f + __expf(-x)); }
__device__ __forceinline__ float tanh_(float x) { return 1.f - 2.f / (__expf(2.f * x) + 1.f); }

#define MFMA __builtin_amdgcn_mfma_f32_16x16x32_bf16

__device__ __forceinline__ s16x8 ld_sc16(const ushort* p) {
  s16x8 v;
  asm volatile("global_load_dwordx4 %0, %1, off sc0 sc1" : "=v"(v) : "v"(p));
  return v;
}
__device__ __forceinline__ void st_sc2(ushort* p, ushort x) {
  unsigned v = x;
  asm volatile("global_store_short %0, %1, off sc0 sc1" :: "v"(p), "v"(v) : "memory");
}
// async global->LDS, 16B per lane; lds base wave-uniform, global addr per-lane
__device__ __forceinline__ void gload16(const ushort* g, ushort* l) {
  __builtin_amdgcn_global_load_lds(
      (const __attribute__((address_space(1))) void*)g,
      (__attribute__((address_space(3))) void*)l, 16, 0, 0);
}

// ---------- transpose + split-convert: dst_{hi,lo}[n][k] = split(src[k][n]) ----------
__global__ void tr_cvt_split(const float* __restrict__ src, ushort* __restrict__ hi,
                             ushort* __restrict__ lo, int kbits, int Nsrc, int total) {
  int K1 = (1 << kbits) - 1;
  for (int i = blockIdx.x * blockDim.x + threadIdx.x; i < total; i += gridDim.x * blockDim.x) {
    int n = i >> kbits, k = i & K1;
    float v = src[(size_t)k * Nsrc + n];
    ushort h = f2bf(v);
    hi[i] = h;
    lo[i] = f2bf(v - bf2f(h));
  }
}

// ---------- split x chunk rows into hi/lo planes (chunk-row order) ----------
__global__ void split_x_chunk(const float* __restrict__ x, ushort* __restrict__ Xh,
                              ushort* __restrict__ Xl, int t0) {
  for (int i = blockIdx.x * blockDim.x + threadIdx.x; i < 1024 * 512;
       i += gridDim.x * blockDim.x) {
    int ar = i >> 9, k = i & 511;
    size_t grow = (size_t)(ar >> 4) * 512 + t0 + (ar & 15);
    float v = x[grow * 512 + k];
    ushort h = f2bf(v);
    Xh[i] = h;
    Xl[i] = f2bf(v - bf2f(h));
  }
}

// ---------- 3-term split GEMM, async global_load_lds staging (r12 PASS) ----------
template <int C_MODE>
__global__ __launch_bounds__(256) void gemm3q(
    const ushort* __restrict__ Ah, const ushort* __restrict__ Al,
    const ushort* __restrict__ Bh, const ushort* __restrict__ Bl,
    float* __restrict__ Cout, const float* __restrict__ bias,
    int M, int N, int K, int t0) {
  __shared__ __align__(16) ushort Ahs[8192];
  __shared__ __align__(16) ushort Als[8192];
  __shared__ __align__(16) ushort Bhs[8192];
  __shared__ __align__(16) ushort Bls[8192];
  const int bm = blockIdx.x, bn = blockIdx.y;
  const int tid = threadIdx.x, lane = tid & 63;
  const int w = tid >> 6;
  const int wm = (w >> 1) * 64, wn = (w & 1) * 64;
  const int lr = lane & 15;
  const int lk = (lane >> 4) * 8;
  const int srow = lane >> 3;          // 0..7 within 8-row block
  const int scol = (lane & 7) * 8;     // element col within 64
  const ushort* gplane = (w == 0) ? Ah : (w == 1) ? Al : (w == 2) ? Bh : Bl;
  ushort* lplane = (w == 0) ? Ahs : (w == 1) ? Als : (w == 2) ? Bhs : Bls;
  const int grow_base = (w < 2) ? bm * 128 : bn * 128;

  f32x4 acc[4][4] = {};
  for (int k0 = 0; k0 < K; k0 += 64) {
#pragma unroll
    for (int j = 0; j < 16; ++j)
      gload16(gplane + (size_t)(grow_base + j * 8 + srow) * K + k0 + scol,
              lplane + j * 512);
    asm volatile("s_waitcnt vmcnt(0)" ::: "memory");
    __syncthreads();
#pragma unroll
    for (int kk = 0; kk < 64; kk += 32) {
      s16x8 ah[4], al[4], bh[4], bl[4];
#pragma unroll
      for (int i = 0; i < 4; ++i) {
        ah[i] = *(const s16x8*)(Ahs + (wm + i * 16 + lr) * 64 + kk + lk);
        al[i] = *(const s16x8*)(Als + (wm + i * 16 + lr) * 64 + kk + lk);
      }
#pragma unroll
      for (int j = 0; j < 4; ++j) {
        bh[j] = *(const s16x8*)(Bhs + (wn + j * 16 + lr) * 64 + kk + lk);
        bl[j] = *(const s16x8*)(Bls + (wn + j * 16 + lr) * 64 + kk + lk);
      }
#pragma unroll
      for (int i = 0; i < 4; ++i)
#pragma unroll
        for (int j = 0; j < 4; ++j) {
          acc[i][j] = MFMA(ah[i], bh[j], acc[i][j], 0, 0, 0);
          acc[i][j] = MFMA(al[i], bh[j], acc[i][j], 0, 0, 0);
          acc[i][j] = MFMA(ah[i], bl[j], acc[i][j], 0, 0, 0);
        }
    }
    __syncthreads();
  }
#pragma unroll
  for (int i = 0; i < 4; ++i)
#pragma unroll
    for (int j = 0; j < 4; ++j)
#pragma unroll
      for (int r = 0; r < 4; ++r) {
        int lrow = bm * 128 + wm + i * 16 + (lane >> 4) * 4 + r;
        int gcol = bn * 128 + wn + j * 16 + lr;
        float v = acc[i][j][r];
        if (C_MODE == 1) {
          size_t grow = (size_t)(lrow >> 4) * 512 + t0 + (lrow & 15);
          Cout[grow * N + gcol] = v + bias[gcol];
        } else {
          Cout[(size_t)lrow * N + gcol] = v;
        }
      }
}

// ---------- flag-array group barrier: 32 WGs/group; 64 lanes poll (2 per flag) ----------
__device__ __forceinline__ void gbarf(unsigned* flags, int wgc, unsigned tgt) {
  asm volatile("s_waitcnt vmcnt(0)" ::: "memory");
  __syncthreads();
  if (threadIdx.x < 64) {
    if (threadIdx.x == 0) {
      unsigned* fp = flags + wgc;
      asm volatile("global_store_dword %0, %1, off sc0 sc1" :: "v"(fp), "v"(tgt) : "memory");
    }
    const unsigned* pp = flags + (threadIdx.x & 31);
    for (;;) {
      unsigned v;
      asm volatile("global_load_dword %0, %1, off sc0 sc1" : "=v"(v) : "v"(pp) : "memory");
      asm volatile("s_waitcnt vmcnt(0)" ::: "memory");
      if (__all(v >= tgt)) break;
    }
  }
  __syncthreads();
}

// ---------- combined two-layer GRU scan (r11/r12 PASS structure) ----------
// Grid 256 WGs x 256 thr. group = blockIdx>>5 (0..7): groups 0-3 = layer0 chunk c0,
// groups 4-7 = layer1 chunk c1 (c<0 => inactive half). Each group: 16 batch rows,
// 32 WGs x 32 cols. 4 waves K-split (256 each) + LDS reduce; thread finalizes 2 elems.
// LDS: Wz/Wr hi (32 cols). Streamed cached: Wz/Wr lo, Wg hi/lo.
// Comm (h, r*h) via sc0sc1 write-through + flag barrier (protocol proven r7-r12;
// XCD-local sc0 fast path attempted r13/r14 -- NOT coherent, do not revisit).
struct ScanArgs {
  const float *P0, *P1;
  const float *bz0, *br0, *bg0, *bz1, *br1, *bg1;
  const ushort *WzrH0, *WzrL0, *WgH0, *WgL0;
  const ushort *WzrH1, *WzrL1, *WgH1, *WgL1;
  const float* h0;
  int c0, c1;
  float *h32g0, *h32g1;
  ushort *hbh0, *hbl0, *hbh1, *hbl1;
  ushort *rhh0, *rhl0, *rhh1, *rhl1;
  ushort *S0h, *S0l, *S1h, *S1l;
  float* hidout;
  unsigned* flags;             // 8 groups x 64-word stride
  unsigned bar_base;           // launch_idx * 33
};

__global__ __launch_bounds__(256) void gru_scan2(ScanArgs A) {
  __shared__ __align__(16) ushort Wzh[32][1032];
  __shared__ __align__(16) ushort Wrh[32][1032];
  __shared__ float red[4][64][17];
  const int tid = threadIdx.x, lane = tid & 63, w = tid >> 6;
  const int group = blockIdx.x >> 5;
  const int wgc = blockIdx.x & 31;
  const int layer = group >> 2;
  const int grp4 = group & 3;
  const int lr = lane & 15, lkq = lane >> 4;
  const int kbase = w * 256;
  const int myrow = lkq * 4 + w;
  const int brow = grp4 * 16 + myrow;

  const int cc = layer ? A.c1 : A.c0;
  if (cc < 0) return;
  const int t0 = cc * TC;

  const float* P = layer ? A.P1 : A.P0;
  const float* bz = layer ? A.bz1 : A.bz0;
  const float* br = layer ? A.br1 : A.br0;
  const float* bg = layer ? A.bg1 : A.bg0;
  const ushort* WzrH = layer ? A.WzrH1 : A.WzrH0;
  const ushort* WzrL = layer ? A.WzrL1 : A.WzrL0;
  const ushort* WgH = layer ? A.WgH1 : A.WgH0;
  const ushort* WgL = layer ? A.WgL1 : A.WgL0;
  float* h32g = layer ? A.h32g1 : A.h32g0;
  ushort* hbh = layer ? A.hbh1 : A.hbh0;
  ushort* hbl = layer ? A.hbl1 : A.hbl0;
  ushort* rhh = layer ? A.rhh1 : A.rhh0;
  ushort* rhl = layer ? A.rhl1 : A.rhl0;
  ushort* Sh = layer ? A.S1h : A.S0h;
  ushort* Sl = layer ? A.S1l : A.S0l;
  unsigned* flags = A.flags + group * 64;
  unsigned tgt = A.bar_base;

  // stage Wz/Wr hi slices (32 cols) into LDS
  {
    const ushort* sz = WzrH + (size_t)(wgc * 32) * 1024;
    const ushort* sr = WzrH + (size_t)(1024 + wgc * 32) * 1024;
#pragma unroll
    for (int j = 0; j < 16; ++j) {
      int id = tid + j * 256;            // 0..4095 int4 slots
      int row = id >> 7, ko = (id & 127) * 8;
      *(int4*)(&Wzh[row][ko]) = *(const int4*)(sz + row * 1024 + ko);
      *(int4*)(&Wrh[row][ko]) = *(const int4*)(sr + row * 1024 + ko);
    }
  }

  const int cz0 = wgc * 32 + lr;
  const float bzc[2] = { bz[cz0], bz[cz0 + 16] };
  const float brc[2] = { br[cz0], br[cz0 + 16] };
  const float bgc[2] = { bg[cz0], bg[cz0 + 16] };
  float h32[2], zv[2] = {};

  if (t0 == 0) {
#pragma unroll
    for (int ct = 0; ct < 2; ++ct) {
      int czc = cz0 + ct * 16;
      float v = A.h0[(size_t)(brow * 2 + layer) * 1024 + czc];
      h32[ct] = v;
      ushort hi = f2bf(v);
      st_sc2(&hbh[brow * 1024 + czc], hi);
      st_sc2(&hbl[brow * 1024 + czc], f2bf(v - bf2f(hi)));
    }
  } else {
#pragma unroll
    for (int ct = 0; ct < 2; ++ct) h32[ct] = h32g[brow * 1024 + cz0 + ct * 16];
  }
  tgt += 1; gbarf(flags, wgc, tgt);   // LDS staging + h init visibility

  const ushort* hhp = hbh + (size_t)(grp4 * 16 + lr) * 1024 + kbase + lkq * 8;
  const ushort* hlp = hbl + (size_t)(grp4 * 16 + lr) * 1024 + kbase + lkq * 8;
  const ushort* rhp = rhh + (size_t)(grp4 * 16 + lr) * 1024 + kbase + lkq * 8;
  const ushort* rlp = rhl + (size_t)(grp4 * 16 + lr) * 1024 + kbase + lkq * 8;
  const ushort* wzl0 = WzrL + (size_t)(wgc * 32 + lr) * 1024 + kbase + lkq * 8;
  const ushort* wzl1 = wzl0 + 16 * 1024;
  const ushort* wrl0 = WzrL + (size_t)(1024 + wgc * 32 + lr) * 1024 + kbase + lkq * 8;
  const ushort* wrl1 = wrl0 + 16 * 1024;
  const ushort* wgh0 = WgH + (size_t)(wgc * 32 + lr) * 1024 + kbase + lkq * 8;
  const ushort* wgh1 = wgh0 + 16 * 1024;
  const ushort* wgl0 = WgL + (size_t)(wgc * 32 + lr) * 1024 + kbase + lkq * 8;
  const ushort* wgl1 = wgl0 + 16 * 1024;

  for (int tl = 0; tl < TC; ++tl) {
    const size_t prow = (size_t)(brow * TC + tl) * 3072;
    // ---- stage 1: partial z,r over this wave's K-quarter, 2 col-tiles ----
    {
      s16x8 hh[8], hl[8];
#pragma unroll
      for (int e = 0; e < 8; ++e) {
        hh[e] = ld_sc16(hhp + e * 32);
        hl[e] = ld_sc16(hlp + e * 32);
      }
      asm volatile("s_waitcnt vmcnt(0)" ::: "memory");
      __builtin_amdgcn_sched_barrier(0);
      f32x4 az0 = {}, az1 = {}, ar0 = {}, ar1 = {};
#pragma unroll
      for (int ks = 0; ks < 8; ++ks) {
        int kc = kbase + ks * 32 + lkq * 8;
        s16x8 wzA = *(const s16x8*)(&Wzh[lr][kc]);
        s16x8 wzB = *(const s16x8*)(&Wzh[16 + lr][kc]);
        s16x8 wrA = *(const s16x8*)(&Wrh[lr][kc]);
        s16x8 wrB = *(const s16x8*)(&Wrh[16 + lr][kc]);
        s16x8 zlA = *(const s16x8*)(wzl0 + ks * 32);
        s16x8 zlB = *(const s16x8*)(wzl1 + ks * 32);
        s16x8 rlA = *(const s16x8*)(wrl0 + ks * 32);
        s16x8 rlB = *(const s16x8*)(wrl1 + ks * 32);
        az0 = MFMA(hh[ks], wzA, az0, 0, 0, 0);
        az0 = MFMA(hl[ks], wzA, az0, 0, 0, 0);
        az0 = MFMA(hh[ks], zlA, az0, 0, 0, 0);
        az1 = MFMA(hh[ks], wzB, az1, 0, 0, 0);
        az1 = MFMA(hl[ks], wzB, az1, 0, 0, 0);
        az1 = MFMA(hh[ks], zlB, az1, 0, 0, 0);
        ar0 = MFMA(hh[ks], wrA, ar0, 0, 0, 0);
        ar0 = MFMA(hl[ks], wrA, ar0, 0, 0, 0);
        ar0 = MFMA(hh[ks], rlA, ar0, 0, 0, 0);
        ar1 = MFMA(hh[ks], wrB, ar1, 0, 0, 0);
        ar1 = MFMA(hl[ks], wrB, ar1, 0, 0, 0);
        ar1 = MFMA(hh[ks], rlB, ar1, 0, 0, 0);
      }
#pragma unroll
      for (int i = 0; i < 4; ++i) {
        red[w][lane][i] = az0[i];      red[w][lane][4 + i] = ar0[i];
        red[w][lane][8 + i] = az1[i];  red[w][lane][12 + i] = ar1[i];
      }
      __syncthreads();
#pragma unroll
      for (int ct = 0; ct < 2; ++ct) {
        int czc = cz0 + ct * 16;
        float azs = red[0][lane][ct * 8 + w] + red[1][lane][ct * 8 + w] +
                    red[2][lane][ct * 8 + w] + red[3][lane][ct * 8 + w];
        float ars = red[0][lane][ct * 8 + 4 + w] + red[1][lane][ct * 8 + 4 + w] +
                    red[2][lane][ct * 8 + 4 + w] + red[3][lane][ct * 8 + 4 + w];
        zv[ct] = sigm(P[prow + czc] + bzc[ct] + azs);
        float rv = sigm(P[prow + 1024 + czc] + brc[ct] + ars);
        float p = rv * h32[ct];
        ushort ph = f2bf(p);
        st_sc2(&rhh[brow * 1024 + czc], ph);
        st_sc2(&rhl[brow * 1024 + czc], f2bf(p - bf2f(ph)));
      }
    }
    tgt += 1; gbarf(flags, wgc, tgt);
    // ---- stage 2: partial g; h update ----
    {
      s16x8 rh8[8], rl8[8];
#pragma unroll
      for (int e = 0; e < 8; ++e) {
        rh8[e] = ld_sc16(rhp + e * 32);
        rl8[e] = ld_sc16(rlp + e * 32);
      }
      asm volatile("s_waitcnt vmcnt(0)" ::: "memory");
      __builtin_amdgcn_sched_barrier(0);
      f32x4 ag0 = {}, ag1 = {};
#pragma unroll
      for (int ks = 0; ks < 8; ++ks) {
        s16x8 ghA = *(const s16x8*)(wgh0 + ks * 32);
        s16x8 ghB = *(const s16x8*)(wgh1 + ks * 32);
        s16x8 glA = *(const s16x8*)(wgl0 + ks * 32);
        s16x8 glB = *(const s16x8*)(wgl1 + ks * 32);
        ag0 = MFMA(rh8[ks], ghA, ag0, 0, 0, 0);
        ag0 = MFMA(rl8[ks], ghA, ag0, 0, 0, 0);
        ag0 = MFMA(rh8[ks], glA, ag0, 0, 0, 0);
        ag1 = MFMA(rh8[ks], ghB, ag1, 0, 0, 0);
        ag1 = MFMA(rl8[ks], ghB, ag1, 0, 0, 0);
        ag1 = MFMA(rh8[ks], glB, ag1, 0, 0, 0);
      }
#pragma unroll
      for (int i = 0; i < 4; ++i) {
        red[w][lane][i] = ag0[i];
        red[w][lane][8 + i] = ag1[i];
      }
      __syncthreads();
#pragma unroll
      for (int ct = 0; ct < 2; ++ct) {
        int czc = cz0 + ct * 16;
        float ags = red[0][lane][ct * 8 + w] + red[1][lane][ct * 8 + w] +
                    red[2][lane][ct * 8 + w] + red[3][lane][ct * 8 + w];
        float g = tanh_(P[prow + 2048 + czc] + bgc[ct] + ags);
        float hn = zv[ct] * h32[ct] + (1.f - zv[ct]) * g;
        h32[ct] = hn;
        ushort hi = f2bf(hn);
        ushort lo = f2bf(hn - bf2f(hi));
        st_sc2(&hbh[brow * 1024 + czc], hi);
        st_sc2(&hbl[brow * 1024 + czc], lo);
        size_t so = (size_t)(brow * TC + tl) * 1024 + czc;
        Sh[so] = hi; Sl[so] = lo;
        if (t0 + tl == 511) A.hidout[(size_t)(brow * 2 + layer) * 1024 + czc] = hn;
      }
    }
    tgt += 1; gbarf(flags, wgc, tgt);
  }
#pragma unroll
  for (int ct = 0; ct < 2; ++ct) h32g[brow * 1024 + cz0 + ct * 16] = h32[ct];
}

// ---------- workspace layout (bytes) ----------
static constexpr size_t OFF_WXT0H   = 0;
static constexpr size_t OFF_WXT0L   = OFF_WXT0H + 3072ull * 512 * 2;
static constexpr size_t OFF_WHZRT0H = OFF_WXT0L + 3072ull * 512 * 2;
static constexpr size_t OFF_WHZRT0L = OFF_WHZRT0H + 2048ull * 1024 * 2;
static constexpr size_t OFF_WHGT0H  = OFF_WHZRT0L + 2048ull * 1024 * 2;
static constexpr size_t OFF_WHGT0L  = OFF_WHGT0H + 1024ull * 1024 * 2;
static constexpr size_t OFF_WXT1H   = OFF_WHGT0L + 1024ull * 1024 * 2;
static constexpr size_t OFF_WXT1L   = OFF_WXT1H + 3072ull * 1024 * 2;
static constexpr size_t OFF_WHZRT1H = OFF_WXT1L + 3072ull * 1024 * 2;
static constexpr size_t OFF_WHZRT1L = OFF_WHZRT1H + 2048ull * 1024 * 2;
static constexpr size_t OFF_WHGT1H  = OFF_WHZRT1L + 2048ull * 1024 * 2;
static constexpr size_t OFF_WHGT1L  = OFF_WHGT1H + 1024ull * 1024 * 2;
static constexpr size_t OFF_WHYTH   = OFF_WHGT1L + 1024ull * 1024 * 2;
static constexpr size_t OFF_WHYTL   = OFF_WHYTH + 512ull * 1024 * 2;
static constexpr size_t OFF_P0      = OFF_WHYTL + 512ull * 1024 * 2;
static constexpr size_t OFF_S0H     = OFF_P0 + 1024ull * 3072 * 4;
static constexpr size_t OFF_S0L     = OFF_S0H + 1024ull * 1024 * 2;
static constexpr size_t OFF_S1H     = OFF_S0L + 1024ull * 1024 * 2;
static constexpr size_t OFF_S1L     = OFF_S1H + 1024ull * 1024 * 2;
static constexpr size_t OFF_HBH0    = OFF_S1L + 1024ull * 1024 * 2;
static constexpr size_t OFF_HBL0    = OFF_HBH0 + 64ull * 1024 * 2;
static constexpr size_t OFF_HBH1    = OFF_HBL0 + 64ull * 1024 * 2;
static constexpr size_t OFF_HBL1    = OFF_HBH1 + 64ull * 1024 * 2;
static constexpr size_t OFF_H320    = OFF_HBL1 + 64ull * 1024 * 2;
static constexpr size_t OFF_H321    = OFF_H320 + 64ull * 1024 * 4;
static constexpr size_t OFF_RHH0    = OFF_H321 + 64ull * 1024 * 4;
static constexpr size_t OFF_RHL0    = OFF_RHH0 + 64ull * 1024 * 2;
static constexpr size_t OFF_RHH1    = OFF_RHL0 + 64ull * 1024 * 2;
static constexpr size_t OFF_RHL1    = OFF_RHH1 + 64ull * 1024 * 2;
static constexpr size_t OFF_FLAGS   = OFF_RHL1 + 64ull * 1024 * 2;
static constexpr size_t OFF_END_SER = OFF_FLAGS + 4096;
static constexpr size_t OFF_P1      = OFF_END_SER;
static constexpr size_t OFF_END_PIPE = OFF_P1 + 1024ull * 3072 * 4;

extern "C" void kernel_launch(void* const* d_in, const int* in_sizes, int n_in,
                              void* d_out, int out_size, void* d_ws, size_t ws_size,
                              hipStream_t stream) {
  if (ws_size < OFF_END_SER) return;  // clean fail: zeros => absmax 12.875 signature
  const bool pipe = (ws_size >= OFF_END_PIPE);

  const float* x     = (const float*)d_in[0];
  const float* h0    = (const float*)d_in[1];
  const float* W_xz0 = (const float*)d_in[2];
  const float* W_hz0 = (const float*)d_in[3];
  const float* b_z0  = (const float*)d_in[4];
  const float* W_xr0 = (const float*)d_in[5];
  const float* W_hr0 = (const float*)d_in[6];
  const float* b_r0  = (const float*)d_in[7];
  const float* W_xg0 = (const float*)d_in[8];
  const float* W_hg0 = (const float*)d_in[9];
  const float* b_g0  = (const float*)d_in[10];
  const float* W_xz1 = (const float*)d_in[11];
  const float* W_hz1 = (const float*)d_in[12];
  const float* b_z1  = (const float*)d_in[13];
  const float* W_xr1 = (const float*)d_in[14];
  const float* W_hr1 = (const float*)d_in[15];
  const float* b_r1  = (const float*)d_in[16];
  const float* W_xg1 = (const float*)d_in[17];
  const float* W_hg1 = (const float*)d_in[18];
  const float* b_g1  = (const float*)d_in[19];
  const float* W_hy  = (const float*)d_in[20];
  const float* b_y   = (const float*)d_in[21];

  char* ws = (char*)d_ws;
  float* out_y   = (float*)d_out;
  float* out_hid = (float*)d_out + 16777216;
  unsigned* flags = (unsigned*)(ws + OFF_FLAGS);

  hipMemsetAsync(flags, 0, 4096, stream);

#define TRS(W, OFF_H, OFF_L, kbits, Nsrc, total) \
  tr_cvt_split<<<2048, 256, 0, stream>>>(W, (ushort*)(ws + OFF_H), (ushort*)(ws + OFF_L), kbits, Nsrc, total)
  TRS(W_xz0, OFF_WXT0H,                  OFF_WXT0L,                   9, 1024, 1024 * 512);
  TRS(W_xr0, OFF_WXT0H + 1024ull*512*2,  OFF_WXT0L + 1024ull*512*2,   9, 1024, 1024 * 512);
  TRS(W_xg0, OFF_WXT0H + 2048ull*512*2,  OFF_WXT0L + 2048ull*512*2,   9, 1024, 1024 * 512);
  TRS(W_hz0, OFF_WHZRT0H,                OFF_WHZRT0L,                10, 1024, 1024 * 1024);
  TRS(W_hr0, OFF_WHZRT0H + 1024ull*1024*2, OFF_WHZRT0L + 1024ull*1024*2, 10, 1024, 1024 * 1024);
  TRS(W_hg0, OFF_WHGT0H,                 OFF_WHGT0L,                 10, 1024, 1024 * 1024);
  TRS(W_xz1, OFF_WXT1H,                  OFF_WXT1L,                  10, 1024, 1024 * 1024);
  TRS(W_xr1, OFF_WXT1H + 1024ull*1024*2, OFF_WXT1L + 1024ull*1024*2, 10, 1024, 1024 * 1024);
  TRS(W_xg1, OFF_WXT1H + 2048ull*1024*2, OFF_WXT1L + 2048ull*1024*2, 10, 1024, 1024 * 1024);
  TRS(W_hz1, OFF_WHZRT1H,                OFF_WHZRT1L,                10, 1024, 1024 * 1024);
  TRS(W_hr1, OFF_WHZRT1H + 1024ull*1024*2, OFF_WHZRT1L + 1024ull*1024*2, 10, 1024, 1024 * 1024);
  TRS(W_hg1, OFF_WHGT1H,                 OFF_WHGT1L,                 10, 1024, 1024 * 1024);
  TRS(W_hy,  OFF_WHYTH,                  OFF_WHYTL,                  10, 512,  512 * 1024);
#undef TRS

  float*  P0  = (float*)(ws + OFF_P0);
  float*  P1  = pipe ? (float*)(ws + OFF_P1) : P0;
  ushort* S0h = (ushort*)(ws + OFF_S0H);
  ushort* S0l = (ushort*)(ws + OFF_S0L);
  ushort* S1h = (ushort*)(ws + OFF_S1H);
  ushort* S1l = (ushort*)(ws + OFF_S1L);
  ushort* Xh  = S1h;  // alias: X live split_x->proj0; S1 live scan->outproj
  ushort* Xl  = S1l;

  ScanArgs sa;
  sa.P0 = P0; sa.P1 = P1;
  sa.bz0 = b_z0; sa.br0 = b_r0; sa.bg0 = b_g0;
  sa.bz1 = b_z1; sa.br1 = b_r1; sa.bg1 = b_g1;
  sa.WzrH0 = (const ushort*)(ws + OFF_WHZRT0H); sa.WzrL0 = (const ushort*)(ws + OFF_WHZRT0L);
  sa.WgH0  = (const ushort*)(ws + OFF_WHGT0H);  sa.WgL0  = (const ushort*)(ws + OFF_WHGT0L);
  sa.WzrH1 = (const ushort*)(ws + OFF_WHZRT1H); sa.WzrL1 = (const ushort*)(ws + OFF_WHZRT1L);
  sa.WgH1  = (const ushort*)(ws + OFF_WHGT1H);  sa.WgL1  = (const ushort*)(ws + OFF_WHGT1L);
  sa.h0 = h0;
  sa.h32g0 = (float*)(ws + OFF_H320); sa.h32g1 = (float*)(ws + OFF_H321);
  sa.hbh0 = (ushort*)(ws + OFF_HBH0); sa.hbl0 = (ushort*)(ws + OFF_HBL0);
  sa.hbh1 = (ushort*)(ws + OFF_HBH1); sa.hbl1 = (ushort*)(ws + OFF_HBL1);
  sa.rhh0 = (ushort*)(ws + OFF_RHH0); sa.rhl0 = (ushort*)(ws + OFF_RHL0);
  sa.rhh1 = (ushort*)(ws + OFF_RHH1); sa.rhl1 = (ushort*)(ws + OFF_RHL1);
  sa.S0h = S0h; sa.S0l = S0l; sa.S1h = S1h; sa.S1l = S1l;
  sa.hidout = out_hid;
  sa.flags = flags;

  const ushort* WXT0H = (const ushort*)(ws + OFF_WXT0H);
  const ushort* WXT0L = (const ushort*)(ws + OFF_WXT0L);
  const ushort* WXT1H = (const ushort*)(ws + OFF_WXT1H);
  const ushort* WXT1L = (const ushort*)(ws + OFF_WXT1L);
  const ushort* WHYH  = (const ushort*)(ws + OFF_WHYTH);
  const ushort* WHYL  = (const ushort*)(ws + OFF_WHYTL);

  unsigned launch_idx = 0;
  if (pipe) {
    for (int lc = 0; lc <= 32; ++lc) {
      int c0 = (lc < 32) ? lc : -1;
      int c1 = lc - 1;
      if (c0 >= 0) {
        split_x_chunk<<<1024, 256, 0, stream>>>(x, Xh, Xl, c0 * TC);
        gemm3q<0><<<dim3(8, 24), 256, 0, stream>>>(Xh, Xl, WXT0H, WXT0L,
                                                   P0, nullptr, 1024, 3072, 512, 0);
      }
      if (c1 >= 0)
        gemm3q<0><<<dim3(8, 24), 256, 0, stream>>>(S0h, S0l, WXT1H, WXT1L,
                                                   P1, nullptr, 1024, 3072, 1024, 0);
      sa.c0 = c0; sa.c1 = c1; sa.bar_base = launch_idx * 33; ++launch_idx;
      gru_scan2<<<256, 256, 0, stream>>>(sa);
      if (c1 >= 0)
        gemm3q<1><<<dim3(8, 4), 256, 0, stream>>>(S1h, S1l, WHYH, WHYL,
                                                  out_y, b_y, 1024, 512, 1024, c1 * TC);
    }
  } else {
    for (int c = 0; c < 32; ++c) {
      split_x_chunk<<<1024, 256, 0, stream>>>(x, Xh, Xl, c * TC);
      gemm3q<0><<<dim3(8, 24), 256, 0, stream>>>(Xh, Xl, WXT0H, WXT0L,
                                                 P0, nullptr, 1024, 3072, 512, 0);
      sa.c0 = c; sa.c1 = -1; sa.bar_base = launch_idx * 33; ++launch_idx;
      gru_scan2<<<256, 256, 0, stream>>>(sa);
      gemm3q<0><<<dim3(8, 24), 256, 0, stream>>>(S0h, S0l, WXT1H, WXT1L,
                                                 P0, nullptr, 1024, 3072, 1024, 0);
      sa.c0 = -1; sa.c1 = c; sa.bar_base = launch_idx * 33; ++launch_idx;
      gru_scan2<<<256, 256, 0, stream>>>(sa);
      gemm3q<1><<<dim3(8, 4), 256, 0, stream>>>(S1h, S1l, WHYH, WHYL,
                                                out_y, b_y, 1024, 512, 1024, c * TC);
    }
  }
}

// Round 16
// 14595.090 us; speedup vs baseline: 1.0436x; 1.0436x over previous
//
#include <hip/hip_runtime.h>

typedef short s16x8 __attribute__((ext_vector_type(8)));
typedef unsigned short us8 __attribute__((ext_vector_type(8)));
typedef float f32x4 __attribute__((ext_vector_type(4)));

#define TC 16   // time-chunk length

// ---------- helpers ----------
__device__ __forceinline__ ushort f2bf(float f) {
  union { float f; unsigned u; } v; v.f = f;
  unsigned u = v.u;
  u += 0x7fffu + ((u >> 16) & 1u);
  return (ushort)(u >> 16);
}
__device__ __forceinline__ float bf2f(ushort h) {
  union { unsigned u; float f; } v; v.u = ((unsigned)h) << 16; return v.f;
}
__device__ __forceinline__ float sigm(float x) { return 1.f / (1.f + __expf(-x)); }
__device__ __forceinline__ float tanh_(float x) { return 1.f - 2.f / (__expf(2.f * x) + 1.f); }

#define MFMA __builtin_amdgcn_mfma_f32_16x16x32_bf16

__device__ __forceinline__ s16x8 ld_sc16(const ushort* p) {
  s16x8 v;
  asm volatile("global_load_dwordx4 %0, %1, off sc0 sc1" : "=v"(v) : "v"(p));
  return v;
}
__device__ __forceinline__ void st_sc2(ushort* p, ushort x) {
  unsigned v = x;
  asm volatile("global_store_short %0, %1, off sc0 sc1" :: "v"(p), "v"(v) : "memory");
}
// async global->LDS, 16B per lane; lds base wave-uniform, global addr per-lane
__device__ __forceinline__ void gload16(const ushort* g, ushort* l) {
  __builtin_amdgcn_global_load_lds(
      (const __attribute__((address_space(1))) void*)g,
      (__attribute__((address_space(3))) void*)l, 16, 0, 0);
}

// ---------- transpose + split-convert: dst_{hi,lo}[n][k] = split(src[k][n]) ----------
__global__ void tr_cvt_split(const float* __restrict__ src, ushort* __restrict__ hi,
                             ushort* __restrict__ lo, int kbits, int Nsrc, int total) {
  int K1 = (1 << kbits) - 1;
  for (int i = blockIdx.x * blockDim.x + threadIdx.x; i < total; i += gridDim.x * blockDim.x) {
    int n = i >> kbits, k = i & K1;
    float v = src[(size_t)k * Nsrc + n];
    ushort h = f2bf(v);
    hi[i] = h;
    lo[i] = f2bf(v - bf2f(h));
  }
}

// ---------- split x chunk rows into hi/lo planes (chunk-row order) ----------
__global__ void split_x_chunk(const float* __restrict__ x, ushort* __restrict__ Xh,
                              ushort* __restrict__ Xl, int t0) {
  for (int i = blockIdx.x * blockDim.x + threadIdx.x; i < 1024 * 512;
       i += gridDim.x * blockDim.x) {
    int ar = i >> 9, k = i & 511;
    size_t grow = (size_t)(ar >> 4) * 512 + t0 + (ar & 15);
    float v = x[grow * 512 + k];
    ushort h = f2bf(v);
    Xh[i] = h;
    Xl[i] = f2bf(v - bf2f(h));
  }
}

// ---------- 3-term split GEMM, async global_load_lds staging (r12 PASS) ----------
template <int C_MODE>
__global__ __launch_bounds__(256) void gemm3q(
    const ushort* __restrict__ Ah, const ushort* __restrict__ Al,
    const ushort* __restrict__ Bh, const ushort* __restrict__ Bl,
    float* __restrict__ Cout, const float* __restrict__ bias,
    int M, int N, int K, int t0) {
  __shared__ __align__(16) ushort Ahs[8192];
  __shared__ __align__(16) ushort Als[8192];
  __shared__ __align__(16) ushort Bhs[8192];
  __shared__ __align__(16) ushort Bls[8192];
  const int bm = blockIdx.x, bn = blockIdx.y;
  const int tid = threadIdx.x, lane = tid & 63;
  const int w = tid >> 6;
  const int wm = (w >> 1) * 64, wn = (w & 1) * 64;
  const int lr = lane & 15;
  const int lk = (lane >> 4) * 8;
  const int srow = lane >> 3;          // 0..7 within 8-row block
  const int scol = (lane & 7) * 8;     // element col within 64
  const ushort* gplane = (w == 0) ? Ah : (w == 1) ? Al : (w == 2) ? Bh : Bl;
  ushort* lplane = (w == 0) ? Ahs : (w == 1) ? Als : (w == 2) ? Bhs : Bls;
  const int grow_base = (w < 2) ? bm * 128 : bn * 128;

  f32x4 acc[4][4] = {};
  for (int k0 = 0; k0 < K; k0 += 64) {
#pragma unroll
    for (int j = 0; j < 16; ++j)
      gload16(gplane + (size_t)(grow_base + j * 8 + srow) * K + k0 + scol,
              lplane + j * 512);
    asm volatile("s_waitcnt vmcnt(0)" ::: "memory");
    __syncthreads();
#pragma unroll
    for (int kk = 0; kk < 64; kk += 32) {
      s16x8 ah[4], al[4], bh[4], bl[4];
#pragma unroll
      for (int i = 0; i < 4; ++i) {
        ah[i] = *(const s16x8*)(Ahs + (wm + i * 16 + lr) * 64 + kk + lk);
        al[i] = *(const s16x8*)(Als + (wm + i * 16 + lr) * 64 + kk + lk);
      }
#pragma unroll
      for (int j = 0; j < 4; ++j) {
        bh[j] = *(const s16x8*)(Bhs + (wn + j * 16 + lr) * 64 + kk + lk);
        bl[j] = *(const s16x8*)(Bls + (wn + j * 16 + lr) * 64 + kk + lk);
      }
#pragma unroll
      for (int i = 0; i < 4; ++i)
#pragma unroll
        for (int j = 0; j < 4; ++j) {
          acc[i][j] = MFMA(ah[i], bh[j], acc[i][j], 0, 0, 0);
          acc[i][j] = MFMA(al[i], bh[j], acc[i][j], 0, 0, 0);
          acc[i][j] = MFMA(ah[i], bl[j], acc[i][j], 0, 0, 0);
        }
    }
    __syncthreads();
  }
#pragma unroll
  for (int i = 0; i < 4; ++i)
#pragma unroll
    for (int j = 0; j < 4; ++j)
#pragma unroll
      for (int r = 0; r < 4; ++r) {
        int lrow = bm * 128 + wm + i * 16 + (lane >> 4) * 4 + r;
        int gcol = bn * 128 + wn + j * 16 + lr;
        float v = acc[i][j][r];
        if (C_MODE == 1) {
          size_t grow = (size_t)(lrow >> 4) * 512 + t0 + (lrow & 15);
          Cout[grow * N + gcol] = v + bias[gcol];
        } else {
          Cout[(size_t)lrow * N + gcol] = v;
        }
      }
}

// ---------- flag-array group barrier: 32 WGs/group; 64 lanes poll (2 per flag) ----------
__device__ __forceinline__ void gbarf(unsigned* flags, int wgc, unsigned tgt) {
  asm volatile("s_waitcnt vmcnt(0)" ::: "memory");
  __syncthreads();
  if (threadIdx.x < 64) {
    if (threadIdx.x == 0) {
      unsigned* fp = flags + wgc;
      asm volatile("global_store_dword %0, %1, off sc0 sc1" :: "v"(fp), "v"(tgt) : "memory");
    }
    const unsigned* pp = flags + (threadIdx.x & 31);
    for (;;) {
      unsigned v;
      asm volatile("global_load_dword %0, %1, off sc0 sc1" : "=v"(v) : "v"(pp) : "memory");
      asm volatile("s_waitcnt vmcnt(0)" ::: "memory");
      if (__all(v >= tgt)) break;
    }
  }
  __syncthreads();
}

// ---------- combined two-layer GRU scan (r12/r15 PASS structure + P prefetch) ----------
// Grid 256 WGs x 256 thr. group = blockIdx>>5 (0..7): groups 0-3 = layer0 chunk c0,
// groups 4-7 = layer1 chunk c1 (c<0 => inactive half). Each group: 16 batch rows,
// 32 WGs x 32 cols. 4 waves K-split (256 each) + LDS reduce; thread finalizes 2 elems.
// LDS: Wz/Wr hi (32 cols). Streamed cached: Wz/Wr lo; Wg hi/lo in registers.
// Comm (h, r*h) via sc0sc1 write-through + flag barrier (proven r7-r15; XCD-local
// sc0 path r13/r14 NOT coherent -- do not revisit).
// r16: all 6 P values for the step loaded at step top, retired under the h-load
// vmcnt(0) -> removes P latency from both finalize serial chains.
struct ScanArgs {
  const float *P0, *P1;
  const float *bz0, *br0, *bg0, *bz1, *br1, *bg1;
  const ushort *WzrH0, *WzrL0, *WgH0, *WgL0;
  const ushort *WzrH1, *WzrL1, *WgH1, *WgL1;
  const float* h0;
  int c0, c1;
  float *h32g0, *h32g1;
  ushort *hbh0, *hbl0, *hbh1, *hbl1;
  ushort *rhh0, *rhl0, *rhh1, *rhl1;
  ushort *S0h, *S0l, *S1h, *S1l;
  float* hidout;
  unsigned* flags;             // 8 groups x 64-word stride
  unsigned bar_base;           // launch_idx * 33
};

__global__ __launch_bounds__(256) void gru_scan2(ScanArgs A) {
  __shared__ __align__(16) ushort Wzh[32][1032];
  __shared__ __align__(16) ushort Wrh[32][1032];
  __shared__ float red[4][64][17];
  const int tid = threadIdx.x, lane = tid & 63, w = tid >> 6;
  const int group = blockIdx.x >> 5;
  const int wgc = blockIdx.x & 31;
  const int layer = group >> 2;
  const int grp4 = group & 3;
  const int lr = lane & 15, lkq = lane >> 4;
  const int kbase = w * 256;
  const int myrow = lkq * 4 + w;
  const int brow = grp4 * 16 + myrow;

  const int cc = layer ? A.c1 : A.c0;
  if (cc < 0) return;
  const int t0 = cc * TC;

  const float* P = layer ? A.P1 : A.P0;
  const float* bz = layer ? A.bz1 : A.bz0;
  const float* br = layer ? A.br1 : A.br0;
  const float* bg = layer ? A.bg1 : A.bg0;
  const ushort* WzrH = layer ? A.WzrH1 : A.WzrH0;
  const ushort* WzrL = layer ? A.WzrL1 : A.WzrL0;
  const ushort* WgH = layer ? A.WgH1 : A.WgH0;
  const ushort* WgL = layer ? A.WgL1 : A.WgL0;
  float* h32g = layer ? A.h32g1 : A.h32g0;
  ushort* hbh = layer ? A.hbh1 : A.hbh0;
  ushort* hbl = layer ? A.hbl1 : A.hbl0;
  ushort* rhh = layer ? A.rhh1 : A.rhh0;
  ushort* rhl = layer ? A.rhl1 : A.rhl0;
  ushort* Sh = layer ? A.S1h : A.S0h;
  ushort* Sl = layer ? A.S1l : A.S0l;
  unsigned* flags = A.flags + group * 64;
  unsigned tgt = A.bar_base;

  // stage Wz/Wr hi slices (32 cols) into LDS
  {
    const ushort* sz = WzrH + (size_t)(wgc * 32) * 1024;
    const ushort* sr = WzrH + (size_t)(1024 + wgc * 32) * 1024;
#pragma unroll
    for (int j = 0; j < 16; ++j) {
      int id = tid + j * 256;            // 0..4095 int4 slots
      int row = id >> 7, ko = (id & 127) * 8;
      *(int4*)(&Wzh[row][ko]) = *(const int4*)(sz + row * 1024 + ko);
      *(int4*)(&Wrh[row][ko]) = *(const int4*)(sr + row * 1024 + ko);
    }
  }

  const int cz0 = wgc * 32 + lr;
  const float bzc[2] = { bz[cz0], bz[cz0 + 16] };
  const float brc[2] = { br[cz0], br[cz0 + 16] };
  const float bgc[2] = { bg[cz0], bg[cz0 + 16] };
  float h32[2], zv[2] = {};

  if (t0 == 0) {
#pragma unroll
    for (int ct = 0; ct < 2; ++ct) {
      int czc = cz0 + ct * 16;
      float v = A.h0[(size_t)(brow * 2 + layer) * 1024 + czc];
      h32[ct] = v;
      ushort hi = f2bf(v);
      st_sc2(&hbh[brow * 1024 + czc], hi);
      st_sc2(&hbl[brow * 1024 + czc], f2bf(v - bf2f(hi)));
    }
  } else {
#pragma unroll
    for (int ct = 0; ct < 2; ++ct) h32[ct] = h32g[brow * 1024 + cz0 + ct * 16];
  }
  tgt += 1; gbarf(flags, wgc, tgt);   // LDS staging + h init visibility

  const ushort* hhp = hbh + (size_t)(grp4 * 16 + lr) * 1024 + kbase + lkq * 8;
  const ushort* hlp = hbl + (size_t)(grp4 * 16 + lr) * 1024 + kbase + lkq * 8;
  const ushort* rhp = rhh + (size_t)(grp4 * 16 + lr) * 1024 + kbase + lkq * 8;
  const ushort* rlp = rhl + (size_t)(grp4 * 16 + lr) * 1024 + kbase + lkq * 8;
  const ushort* wzl0 = WzrL + (size_t)(wgc * 32 + lr) * 1024 + kbase + lkq * 8;
  const ushort* wzl1 = wzl0 + 16 * 1024;
  const ushort* wrl0 = WzrL + (size_t)(1024 + wgc * 32 + lr) * 1024 + kbase + lkq * 8;
  const ushort* wrl1 = wrl0 + 16 * 1024;
  const ushort* wgh0 = WgH + (size_t)(wgc * 32 + lr) * 1024 + kbase + lkq * 8;
  const ushort* wgh1 = wgh0 + 16 * 1024;
  const ushort* wgl0 = WgL + (size_t)(wgc * 32 + lr) * 1024 + kbase + lkq * 8;
  const ushort* wgl1 = wgl0 + 16 * 1024;

  for (int tl = 0; tl < TC; ++tl) {
    const size_t prow = (size_t)(brow * TC + tl) * 3072;
    // ---- P prefetch: all 6 step inputs issued before the h loads; they retire
    //      under the same vmcnt(0) as the sc-h loads (latency fully hidden).
    float pz[2], pr[2], pg[2];
#pragma unroll
    for (int ct = 0; ct < 2; ++ct) {
      int czc = cz0 + ct * 16;
      pz[ct] = P[prow + czc];
      pr[ct] = P[prow + 1024 + czc];
      pg[ct] = P[prow + 2048 + czc];
    }
    // ---- stage 1: partial z,r over this wave's K-quarter, 2 col-tiles ----
    {
      s16x8 hh[8], hl[8];
#pragma unroll
      for (int e = 0; e < 8; ++e) {
        hh[e] = ld_sc16(hhp + e * 32);
        hl[e] = ld_sc16(hlp + e * 32);
      }
      asm volatile("s_waitcnt vmcnt(0)" ::: "memory");
      __builtin_amdgcn_sched_barrier(0);
      f32x4 az0 = {}, az1 = {}, ar0 = {}, ar1 = {};
#pragma unroll
      for (int ks = 0; ks < 8; ++ks) {
        int kc = kbase + ks * 32 + lkq * 8;
        s16x8 wzA = *(const s16x8*)(&Wzh[lr][kc]);
        s16x8 wzB = *(const s16x8*)(&Wzh[16 + lr][kc]);
        s16x8 wrA = *(const s16x8*)(&Wrh[lr][kc]);
        s16x8 wrB = *(const s16x8*)(&Wrh[16 + lr][kc]);
        s16x8 zlA = *(const s16x8*)(wzl0 + ks * 32);
        s16x8 zlB = *(const s16x8*)(wzl1 + ks * 32);
        s16x8 rlA = *(const s16x8*)(wrl0 + ks * 32);
        s16x8 rlB = *(const s16x8*)(wrl1 + ks * 32);
        az0 = MFMA(hh[ks], wzA, az0, 0, 0, 0);
        az0 = MFMA(hl[ks], wzA, az0, 0, 0, 0);
        az0 = MFMA(hh[ks], zlA, az0, 0, 0, 0);
        az1 = MFMA(hh[ks], wzB, az1, 0, 0, 0);
        az1 = MFMA(hl[ks], wzB, az1, 0, 0, 0);
        az1 = MFMA(hh[ks], zlB, az1, 0, 0, 0);
        ar0 = MFMA(hh[ks], wrA, ar0, 0, 0, 0);
        ar0 = MFMA(hl[ks], wrA, ar0, 0, 0, 0);
        ar0 = MFMA(hh[ks], rlA, ar0, 0, 0, 0);
        ar1 = MFMA(hh[ks], wrB, ar1, 0, 0, 0);
        ar1 = MFMA(hl[ks], wrB, ar1, 0, 0, 0);
        ar1 = MFMA(hh[ks], rlB, ar1, 0, 0, 0);
      }
#pragma unroll
      for (int i = 0; i < 4; ++i) {
        red[w][lane][i] = az0[i];      red[w][lane][4 + i] = ar0[i];
        red[w][lane][8 + i] = az1[i];  red[w][lane][12 + i] = ar1[i];
      }
      __syncthreads();
#pragma unroll
      for (int ct = 0; ct < 2; ++ct) {
        int czc = cz0 + ct * 16;
        float azs = red[0][lane][ct * 8 + w] + red[1][lane][ct * 8 + w] +
                    red[2][lane][ct * 8 + w] + red[3][lane][ct * 8 + w];
        float ars = red[0][lane][ct * 8 + 4 + w] + red[1][lane][ct * 8 + 4 + w] +
                    red[2][lane][ct * 8 + 4 + w] + red[3][lane][ct * 8 + 4 + w];
        zv[ct] = sigm(pz[ct] + bzc[ct] + azs);
        float rv = sigm(pr[ct] + brc[ct] + ars);
        float p = rv * h32[ct];
        ushort ph = f2bf(p);
        st_sc2(&rhh[brow * 1024 + czc], ph);
        st_sc2(&rhl[brow * 1024 + czc], f2bf(p - bf2f(ph)));
      }
    }
    tgt += 1; gbarf(flags, wgc, tgt);
    // ---- stage 2: partial g; h update ----
    {
      s16x8 rh8[8], rl8[8];
#pragma unroll
      for (int e = 0; e < 8; ++e) {
        rh8[e] = ld_sc16(rhp + e * 32);
        rl8[e] = ld_sc16(rlp + e * 32);
      }
      asm volatile("s_waitcnt vmcnt(0)" ::: "memory");
      __builtin_amdgcn_sched_barrier(0);
      f32x4 ag0 = {}, ag1 = {};
#pragma unroll
      for (int ks = 0; ks < 8; ++ks) {
        s16x8 ghA = *(const s16x8*)(wgh0 + ks * 32);
        s16x8 ghB = *(const s16x8*)(wgh1 + ks * 32);
        s16x8 glA = *(const s16x8*)(wgl0 + ks * 32);
        s16x8 glB = *(const s16x8*)(wgl1 + ks * 32);
        ag0 = MFMA(rh8[ks], ghA, ag0, 0, 0, 0);
        ag0 = MFMA(rl8[ks], ghA, ag0, 0, 0, 0);
        ag0 = MFMA(rh8[ks], glA, ag0, 0, 0, 0);
        ag1 = MFMA(rh8[ks], ghB, ag1, 0, 0, 0);
        ag1 = MFMA(rl8[ks], ghB, ag1, 0, 0, 0);
        ag1 = MFMA(rh8[ks], glB, ag1, 0, 0, 0);
      }
#pragma unroll
      for (int i = 0; i < 4; ++i) {
        red[w][lane][i] = ag0[i];
        red[w][lane][8 + i] = ag1[i];
      }
      __syncthreads();
#pragma unroll
      for (int ct = 0; ct < 2; ++ct) {
        int czc = cz0 + ct * 16;
        float ags = red[0][lane][ct * 8 + w] + red[1][lane][ct * 8 + w] +
                    red[2][lane][ct * 8 + w] + red[3][lane][ct * 8 + w];
        float g = tanh_(pg[ct] + bgc[ct] + ags);
        float hn = zv[ct] * h32[ct] + (1.f - zv[ct]) * g;
        h32[ct] = hn;
        ushort hi = f2bf(hn);
        ushort lo = f2bf(hn - bf2f(hi));
        st_sc2(&hbh[brow * 1024 + czc], hi);
        st_sc2(&hbl[brow * 1024 + czc], lo);
        size_t so = (size_t)(brow * TC + tl) * 1024 + czc;
        Sh[so] = hi; Sl[so] = lo;
        if (t0 + tl == 511) A.hidout[(size_t)(brow * 2 + layer) * 1024 + czc] = hn;
      }
    }
    tgt += 1; gbarf(flags, wgc, tgt);
  }
#pragma unroll
  for (int ct = 0; ct < 2; ++ct) h32g[brow * 1024 + cz0 + ct * 16] = h32[ct];
}

// ---------- workspace layout (bytes) ----------
static constexpr size_t OFF_WXT0H   = 0;
static constexpr size_t OFF_WXT0L   = OFF_WXT0H + 3072ull * 512 * 2;
static constexpr size_t OFF_WHZRT0H = OFF_WXT0L + 3072ull * 512 * 2;
static constexpr size_t OFF_WHZRT0L = OFF_WHZRT0H + 2048ull * 1024 * 2;
static constexpr size_t OFF_WHGT0H  = OFF_WHZRT0L + 2048ull * 1024 * 2;
static constexpr size_t OFF_WHGT0L  = OFF_WHGT0H + 1024ull * 1024 * 2;
static constexpr size_t OFF_WXT1H   = OFF_WHGT0L + 1024ull * 1024 * 2;
static constexpr size_t OFF_WXT1L   = OFF_WXT1H + 3072ull * 1024 * 2;
static constexpr size_t OFF_WHZRT1H = OFF_WXT1L + 3072ull * 1024 * 2;
static constexpr size_t OFF_WHZRT1L = OFF_WHZRT1H + 2048ull * 1024 * 2;
static constexpr size_t OFF_WHGT1H  = OFF_WHZRT1L + 2048ull * 1024 * 2;
static constexpr size_t OFF_WHGT1L  = OFF_WHGT1H + 1024ull * 1024 * 2;
static constexpr size_t OFF_WHYTH   = OFF_WHGT1L + 1024ull * 1024 * 2;
static constexpr size_t OFF_WHYTL   = OFF_WHYTH + 512ull * 1024 * 2;
static constexpr size_t OFF_P0      = OFF_WHYTL + 512ull * 1024 * 2;
static constexpr size_t OFF_S0H     = OFF_P0 + 1024ull * 3072 * 4;
static constexpr size_t OFF_S0L     = OFF_S0H + 1024ull * 1024 * 2;
static constexpr size_t OFF_S1H     = OFF_S0L + 1024ull * 1024 * 2;
static constexpr size_t OFF_S1L     = OFF_S1H + 1024ull * 1024 * 2;
static constexpr size_t OFF_HBH0    = OFF_S1L + 1024ull * 1024 * 2;
static constexpr size_t OFF_HBL0    = OFF_HBH0 + 64ull * 1024 * 2;
static constexpr size_t OFF_HBH1    = OFF_HBL0 + 64ull * 1024 * 2;
static constexpr size_t OFF_HBL1    = OFF_HBH1 + 64ull * 1024 * 2;
static constexpr size_t OFF_H320    = OFF_HBL1 + 64ull * 1024 * 2;
static constexpr size_t OFF_H321    = OFF_H320 + 64ull * 1024 * 4;
static constexpr size_t OFF_RHH0    = OFF_H321 + 64ull * 1024 * 4;
static constexpr size_t OFF_RHL0    = OFF_RHH0 + 64ull * 1024 * 2;
static constexpr size_t OFF_RHH1    = OFF_RHL0 + 64ull * 1024 * 2;
static constexpr size_t OFF_RHL1    = OFF_RHH1 + 64ull * 1024 * 2;
static constexpr size_t OFF_FLAGS   = OFF_RHL1 + 64ull * 1024 * 2;
static constexpr size_t OFF_END_SER = OFF_FLAGS + 4096;
static constexpr size_t OFF_P1      = OFF_END_SER;
static constexpr size_t OFF_END_PIPE = OFF_P1 + 1024ull * 3072 * 4;

extern "C" void kernel_launch(void* const* d_in, const int* in_sizes, int n_in,
                              void* d_out, int out_size, void* d_ws, size_t ws_size,
                              hipStream_t stream) {
  if (ws_size < OFF_END_SER) return;  // clean fail: zeros => absmax 12.875 signature
  const bool pipe = (ws_size >= OFF_END_PIPE);

  const float* x     = (const float*)d_in[0];
  const float* h0    = (const float*)d_in[1];
  const float* W_xz0 = (const float*)d_in[2];
  const float* W_hz0 = (const float*)d_in[3];
  const float* b_z0  = (const float*)d_in[4];
  const float* W_xr0 = (const float*)d_in[5];
  const float* W_hr0 = (const float*)d_in[6];
  const float* b_r0  = (const float*)d_in[7];
  const float* W_xg0 = (const float*)d_in[8];
  const float* W_hg0 = (const float*)d_in[9];
  const float* b_g0  = (const float*)d_in[10];
  const float* W_xz1 = (const float*)d_in[11];
  const float* W_hz1 = (const float*)d_in[12];
  const float* b_z1  = (const float*)d_in[13];
  const float* W_xr1 = (const float*)d_in[14];
  const float* W_hr1 = (const float*)d_in[15];
  const float* b_r1  = (const float*)d_in[16];
  const float* W_xg1 = (const float*)d_in[17];
  const float* W_hg1 = (const float*)d_in[18];
  const float* b_g1  = (const float*)d_in[19];
  const float* W_hy  = (const float*)d_in[20];
  const float* b_y   = (const float*)d_in[21];

  char* ws = (char*)d_ws;
  float* out_y   = (float*)d_out;
  float* out_hid = (float*)d_out + 16777216;
  unsigned* flags = (unsigned*)(ws + OFF_FLAGS);

  hipMemsetAsync(flags, 0, 4096, stream);

#define TRS(W, OFF_H, OFF_L, kbits, Nsrc, total) \
  tr_cvt_split<<<2048, 256, 0, stream>>>(W, (ushort*)(ws + OFF_H), (ushort*)(ws + OFF_L), kbits, Nsrc, total)
  TRS(W_xz0, OFF_WXT0H,                  OFF_WXT0L,                   9, 1024, 1024 * 512);
  TRS(W_xr0, OFF_WXT0H + 1024ull*512*2,  OFF_WXT0L + 1024ull*512*2,   9, 1024, 1024 * 512);
  TRS(W_xg0, OFF_WXT0H + 2048ull*512*2,  OFF_WXT0L + 2048ull*512*2,   9, 1024, 1024 * 512);
  TRS(W_hz0, OFF_WHZRT0H,                OFF_WHZRT0L,                10, 1024, 1024 * 1024);
  TRS(W_hr0, OFF_WHZRT0H + 1024ull*1024*2, OFF_WHZRT0L + 1024ull*1024*2, 10, 1024, 1024 * 1024);
  TRS(W_hg0, OFF_WHGT0H,                 OFF_WHGT0L,                 10, 1024, 1024 * 1024);
  TRS(W_xz1, OFF_WXT1H,                  OFF_WXT1L,                  10, 1024, 1024 * 1024);
  TRS(W_xr1, OFF_WXT1H + 1024ull*1024*2, OFF_WXT1L + 1024ull*1024*2, 10, 1024, 1024 * 1024);
  TRS(W_xg1, OFF_WXT1H + 2048ull*1024*2, OFF_WXT1L + 2048ull*1024*2, 10, 1024, 1024 * 1024);
  TRS(W_hz1, OFF_WHZRT1H,                OFF_WHZRT1L,                10, 1024, 1024 * 1024);
  TRS(W_hr1, OFF_WHZRT1H + 1024ull*1024*2, OFF_WHZRT1L + 1024ull*1024*2, 10, 1024, 1024 * 1024);
  TRS(W_hg1, OFF_WHGT1H,                 OFF_WHGT1L,                 10, 1024, 1024 * 1024);
  TRS(W_hy,  OFF_WHYTH,                  OFF_WHYTL,                  10, 512,  512 * 1024);
#undef TRS

  float*  P0  = (float*)(ws + OFF_P0);
  float*  P1  = pipe ? (float*)(ws + OFF_P1) : P0;
  ushort* S0h = (ushort*)(ws + OFF_S0H);
  ushort* S0l = (ushort*)(ws + OFF_S0L);
  ushort* S1h = (ushort*)(ws + OFF_S1H);
  ushort* S1l = (ushort*)(ws + OFF_S1L);
  ushort* Xh  = S1h;  // alias: X live split_x->proj0; S1 live scan->outproj
  ushort* Xl  = S1l;

  ScanArgs sa;
  sa.P0 = P0; sa.P1 = P1;
  sa.bz0 = b_z0; sa.br0 = b_r0; sa.bg0 = b_g0;
  sa.bz1 = b_z1; sa.br1 = b_r1; sa.bg1 = b_g1;
  sa.WzrH0 = (const ushort*)(ws + OFF_WHZRT0H); sa.WzrL0 = (const ushort*)(ws + OFF_WHZRT0L);
  sa.WgH0  = (const ushort*)(ws + OFF_WHGT0H);  sa.WgL0  = (const ushort*)(ws + OFF_WHGT0L);
  sa.WzrH1 = (const ushort*)(ws + OFF_WHZRT1H); sa.WzrL1 = (const ushort*)(ws + OFF_WHZRT1L);
  sa.WgH1  = (const ushort*)(ws + OFF_WHGT1H);  sa.WgL1  = (const ushort*)(ws + OFF_WHGT1L);
  sa.h0 = h0;
  sa.h32g0 = (float*)(ws + OFF_H320); sa.h32g1 = (float*)(ws + OFF_H321);
  sa.hbh0 = (ushort*)(ws + OFF_HBH0); sa.hbl0 = (ushort*)(ws + OFF_HBL0);
  sa.hbh1 = (ushort*)(ws + OFF_HBH1); sa.hbl1 = (ushort*)(ws + OFF_HBL1);
  sa.rhh0 = (ushort*)(ws + OFF_RHH0); sa.rhl0 = (ushort*)(ws + OFF_RHL0);
  sa.rhh1 = (ushort*)(ws + OFF_RHH1); sa.rhl1 = (ushort*)(ws + OFF_RHL1);
  sa.S0h = S0h; sa.S0l = S0l; sa.S1h = S1h; sa.S1l = S1l;
  sa.hidout = out_hid;
  sa.flags = flags;

  const ushort* WXT0H = (const ushort*)(ws + OFF_WXT0H);
  const ushort* WXT0L = (const ushort*)(ws + OFF_WXT0L);
  const ushort* WXT1H = (const ushort*)(ws + OFF_WXT1H);
  const ushort* WXT1L = (const ushort*)(ws + OFF_WXT1L);
  const ushort* WHYH  = (const ushort*)(ws + OFF_WHYTH);
  const ushort* WHYL  = (const ushort*)(ws + OFF_WHYTL);

  unsigned launch_idx = 0;
  if (pipe) {
    for (int lc = 0; lc <= 32; ++lc) {
      int c0 = (lc < 32) ? lc : -1;
      int c1 = lc - 1;
      if (c0 >= 0) {
        split_x_chunk<<<1024, 256, 0, stream>>>(x, Xh, Xl, c0 * TC);
        gemm3q<0><<<dim3(8, 24), 256, 0, stream>>>(Xh, Xl, WXT0H, WXT0L,
                                                   P0, nullptr, 1024, 3072, 512, 0);
      }
      if (c1 >= 0)
        gemm3q<0><<<dim3(8, 24), 256, 0, stream>>>(S0h, S0l, WXT1H, WXT1L,
                                                   P1, nullptr, 1024, 3072, 1024, 0);
      sa.c0 = c0; sa.c1 = c1; sa.bar_base = launch_idx * 33; ++launch_idx;
      gru_scan2<<<256, 256, 0, stream>>>(sa);
      if (c1 >= 0)
        gemm3q<1><<<dim3(8, 4), 256, 0, stream>>>(S1h, S1l, WHYH, WHYL,
                                                  out_y, b_y, 1024, 512, 1024, c1 * TC);
    }
  } else {
    for (int c = 0; c < 32; ++c) {
      split_x_chunk<<<1024, 256, 0, stream>>>(x, Xh, Xl, c * TC);
      gemm3q<0><<<dim3(8, 24), 256, 0, stream>>>(Xh, Xl, WXT0H, WXT0L,
                                                 P0, nullptr, 1024, 3072, 512, 0);
      sa.c0 = c; sa.c1 = -1; sa.bar_base = launch_idx * 33; ++launch_idx;
      gru_scan2<<<256, 256, 0, stream>>>(sa);
      gemm3q<0><<<dim3(8, 24), 256, 0, stream>>>(S0h, S0l, WXT1H, WXT1L,
                                                 P0, nullptr, 1024, 3072, 1024, 0);
      sa.c0 = -1; sa.c1 = c; sa.bar_base = launch_idx * 33; ++launch_idx;
      gru_scan2<<<256, 256, 0, stream>>>(sa);
      gemm3q<1><<<dim3(8, 4), 256, 0, stream>>>(S1h, S1l, WHYH, WHYL,
                                                out_y, b_y, 1024, 512, 1024, c * TC);
    }
  }
}

// Round 17
// 14243.919 us; speedup vs baseline: 1.0694x; 1.0247x over previous
//
#include <hip/hip_runtime.h>

typedef short s16x8 __attribute__((ext_vector_type(8)));
typedef unsigned short us8 __attribute__((ext_vector_type(8)));
typedef float f32x4 __attribute__((ext_vector_type(4)));

#define TC 16   // time-chunk length

// ---------- helpers ----------
__device__ __forceinline__ ushort f2bf(float f) {
  union { float f; unsigned u; } v; v.f = f;
  unsigned u = v.u;
  u += 0x7fffu + ((u >> 16) & 1u);
  return (ushort)(u >> 16);
}
__device__ __forceinline__ float bf2f(ushort h) {
  union { unsigned u; float f; } v; v.u = ((unsigned)h) << 16; return v.f;
}
__device__ __forceinline__ float sigm(float x) { return 1.f / (1.f + __expf(-x)); }
__device__ __forceinline__ float tanh_(float x) { return 1.f - 2.f / (__expf(2.f * x) + 1.f); }

#define MFMA __builtin_amdgcn_mfma_f32_16x16x32_bf16

__device__ __forceinline__ s16x8 ld_sc16(const ushort* p) {
  s16x8 v;
  asm volatile("global_load_dwordx4 %0, %1, off sc0 sc1" : "=v"(v) : "v"(p));
  return v;
}
__device__ __forceinline__ void st_sc2(ushort* p, ushort x) {
  unsigned v = x;
  asm volatile("global_store_short %0, %1, off sc0 sc1" :: "v"(p), "v"(v) : "memory");
}
// async global->LDS, 16B per lane; lds base wave-uniform, global addr per-lane
__device__ __forceinline__ void gload16(const ushort* g, ushort* l) {
  __builtin_amdgcn_global_load_lds(
      (const __attribute__((address_space(1))) void*)g,
      (__attribute__((address_space(3))) void*)l, 16, 0, 0);
}

// ---------- transpose + split-convert: dst_{hi,lo}[n][k] = split(src[k][n]) ----------
__global__ void tr_cvt_split(const float* __restrict__ src, ushort* __restrict__ hi,
                             ushort* __restrict__ lo, int kbits, int Nsrc, int total) {
  int K1 = (1 << kbits) - 1;
  for (int i = blockIdx.x * blockDim.x + threadIdx.x; i < total; i += gridDim.x * blockDim.x) {
    int n = i >> kbits, k = i & K1;
    float v = src[(size_t)k * Nsrc + n];
    ushort h = f2bf(v);
    hi[i] = h;
    lo[i] = f2bf(v - bf2f(h));
  }
}

// ---------- split x chunk rows into hi/lo planes (chunk-row order) ----------
__global__ void split_x_chunk(const float* __restrict__ x, ushort* __restrict__ Xh,
                              ushort* __restrict__ Xl, int t0) {
  for (int i = blockIdx.x * blockDim.x + threadIdx.x; i < 1024 * 512;
       i += gridDim.x * blockDim.x) {
    int ar = i >> 9, k = i & 511;
    size_t grow = (size_t)(ar >> 4) * 512 + t0 + (ar & 15);
    float v = x[grow * 512 + k];
    ushort h = f2bf(v);
    Xh[i] = h;
    Xl[i] = f2bf(v - bf2f(h));
  }
}

// ---------- 3-term split GEMM, async global_load_lds staging (r12 PASS) ----------
template <int C_MODE>
__global__ __launch_bounds__(256) void gemm3q(
    const ushort* __restrict__ Ah, const ushort* __restrict__ Al,
    const ushort* __restrict__ Bh, const ushort* __restrict__ Bl,
    float* __restrict__ Cout, const float* __restrict__ bias,
    int M, int N, int K, int t0) {
  __shared__ __align__(16) ushort Ahs[8192];
  __shared__ __align__(16) ushort Als[8192];
  __shared__ __align__(16) ushort Bhs[8192];
  __shared__ __align__(16) ushort Bls[8192];
  const int bm = blockIdx.x, bn = blockIdx.y;
  const int tid = threadIdx.x, lane = tid & 63;
  const int w = tid >> 6;
  const int wm = (w >> 1) * 64, wn = (w & 1) * 64;
  const int lr = lane & 15;
  const int lk = (lane >> 4) * 8;
  const int srow = lane >> 3;          // 0..7 within 8-row block
  const int scol = (lane & 7) * 8;     // element col within 64
  const ushort* gplane = (w == 0) ? Ah : (w == 1) ? Al : (w == 2) ? Bh : Bl;
  ushort* lplane = (w == 0) ? Ahs : (w == 1) ? Als : (w == 2) ? Bhs : Bls;
  const int grow_base = (w < 2) ? bm * 128 : bn * 128;

  f32x4 acc[4][4] = {};
  for (int k0 = 0; k0 < K; k0 += 64) {
#pragma unroll
    for (int j = 0; j < 16; ++j)
      gload16(gplane + (size_t)(grow_base + j * 8 + srow) * K + k0 + scol,
              lplane + j * 512);
    asm volatile("s_waitcnt vmcnt(0)" ::: "memory");
    __syncthreads();
#pragma unroll
    for (int kk = 0; kk < 64; kk += 32) {
      s16x8 ah[4], al[4], bh[4], bl[4];
#pragma unroll
      for (int i = 0; i < 4; ++i) {
        ah[i] = *(const s16x8*)(Ahs + (wm + i * 16 + lr) * 64 + kk + lk);
        al[i] = *(const s16x8*)(Als + (wm + i * 16 + lr) * 64 + kk + lk);
      }
#pragma unroll
      for (int j = 0; j < 4; ++j) {
        bh[j] = *(const s16x8*)(Bhs + (wn + j * 16 + lr) * 64 + kk + lk);
        bl[j] = *(const s16x8*)(Bls + (wn + j * 16 + lr) * 64 + kk + lk);
      }
#pragma unroll
      for (int i = 0; i < 4; ++i)
#pragma unroll
        for (int j = 0; j < 4; ++j) {
          acc[i][j] = MFMA(ah[i], bh[j], acc[i][j], 0, 0, 0);
          acc[i][j] = MFMA(al[i], bh[j], acc[i][j], 0, 0, 0);
          acc[i][j] = MFMA(ah[i], bl[j], acc[i][j], 0, 0, 0);
        }
    }
    __syncthreads();
  }
#pragma unroll
  for (int i = 0; i < 4; ++i)
#pragma unroll
    for (int j = 0; j < 4; ++j)
#pragma unroll
      for (int r = 0; r < 4; ++r) {
        int lrow = bm * 128 + wm + i * 16 + (lane >> 4) * 4 + r;
        int gcol = bn * 128 + wn + j * 16 + lr;
        float v = acc[i][j][r];
        if (C_MODE == 1) {
          size_t grow = (size_t)(lrow >> 4) * 512 + t0 + (lrow & 15);
          Cout[grow * N + gcol] = v + bias[gcol];
        } else {
          Cout[(size_t)lrow * N + gcol] = v;
        }
      }
}

// ---------- flag-array group barrier: 32 WGs/group; 64 lanes poll (2 per flag) ----------
__device__ __forceinline__ void gbarf(unsigned* flags, int wgc, unsigned tgt) {
  asm volatile("s_waitcnt vmcnt(0)" ::: "memory");
  __syncthreads();
  if (threadIdx.x < 64) {
    if (threadIdx.x == 0) {
      unsigned* fp = flags + wgc;
      asm volatile("global_store_dword %0, %1, off sc0 sc1" :: "v"(fp), "v"(tgt) : "memory");
    }
    const unsigned* pp = flags + (threadIdx.x & 31);
    for (;;) {
      unsigned v;
      asm volatile("global_load_dword %0, %1, off sc0 sc1" : "=v"(v) : "v"(pp) : "memory");
      asm volatile("s_waitcnt vmcnt(0)" ::: "memory");
      if (__all(v >= tgt)) break;
    }
  }
  __syncthreads();
}

// ---------- combined two-layer GRU scan (r16 PASS + z-gate deferral) ----------
// Stage 1: r-matmul only -> shorter pre-barrier chain. Stage 2: z-matmul on the
// h fragments retained in registers runs under the rh sc-load shadow, then g.
// Same MFMA ops/order as r16 -> bit-identical numerics.
struct ScanArgs {
  const float *P0, *P1;
  const float *bz0, *br0, *bg0, *bz1, *br1, *bg1;
  const ushort *WzrH0, *WzrL0, *WgH0, *WgL0;
  const ushort *WzrH1, *WzrL1, *WgH1, *WgL1;
  const float* h0;
  int c0, c1;
  float *h32g0, *h32g1;
  ushort *hbh0, *hbl0, *hbh1, *hbl1;
  ushort *rhh0, *rhl0, *rhh1, *rhl1;
  ushort *S0h, *S0l, *S1h, *S1l;
  float* hidout;
  unsigned* flags;             // 8 groups x 64-word stride
  unsigned bar_base;           // launch_idx * 33
};

__global__ __launch_bounds__(256) void gru_scan2(ScanArgs A) {
  __shared__ __align__(16) ushort Wzh[32][1032];
  __shared__ __align__(16) ushort Wrh[32][1032];
  __shared__ float red[4][64][17];
  const int tid = threadIdx.x, lane = tid & 63, w = tid >> 6;
  const int group = blockIdx.x >> 5;
  const int wgc = blockIdx.x & 31;
  const int layer = group >> 2;
  const int grp4 = group & 3;
  const int lr = lane & 15, lkq = lane >> 4;
  const int kbase = w * 256;
  const int myrow = lkq * 4 + w;
  const int brow = grp4 * 16 + myrow;

  const int cc = layer ? A.c1 : A.c0;
  if (cc < 0) return;
  const int t0 = cc * TC;

  const float* P = layer ? A.P1 : A.P0;
  const float* bz = layer ? A.bz1 : A.bz0;
  const float* br = layer ? A.br1 : A.br0;
  const float* bg = layer ? A.bg1 : A.bg0;
  const ushort* WzrH = layer ? A.WzrH1 : A.WzrH0;
  const ushort* WzrL = layer ? A.WzrL1 : A.WzrL0;
  const ushort* WgH = layer ? A.WgH1 : A.WgH0;
  const ushort* WgL = layer ? A.WgL1 : A.WgL0;
  float* h32g = layer ? A.h32g1 : A.h32g0;
  ushort* hbh = layer ? A.hbh1 : A.hbh0;
  ushort* hbl = layer ? A.hbl1 : A.hbl0;
  ushort* rhh = layer ? A.rhh1 : A.rhh0;
  ushort* rhl = layer ? A.rhl1 : A.rhl0;
  ushort* Sh = layer ? A.S1h : A.S0h;
  ushort* Sl = layer ? A.S1l : A.S0l;
  unsigned* flags = A.flags + group * 64;
  unsigned tgt = A.bar_base;

  // stage Wz/Wr hi slices (32 cols) into LDS
  {
    const ushort* sz = WzrH + (size_t)(wgc * 32) * 1024;
    const ushort* sr = WzrH + (size_t)(1024 + wgc * 32) * 1024;
#pragma unroll
    for (int j = 0; j < 16; ++j) {
      int id = tid + j * 256;            // 0..4095 int4 slots
      int row = id >> 7, ko = (id & 127) * 8;
      *(int4*)(&Wzh[row][ko]) = *(const int4*)(sz + row * 1024 + ko);
      *(int4*)(&Wrh[row][ko]) = *(const int4*)(sr + row * 1024 + ko);
    }
  }

  const int cz0 = wgc * 32 + lr;
  const float bzc[2] = { bz[cz0], bz[cz0 + 16] };
  const float brc[2] = { br[cz0], br[cz0 + 16] };
  const float bgc[2] = { bg[cz0], bg[cz0 + 16] };
  float h32[2];

  if (t0 == 0) {
#pragma unroll
    for (int ct = 0; ct < 2; ++ct) {
      int czc = cz0 + ct * 16;
      float v = A.h0[(size_t)(brow * 2 + layer) * 1024 + czc];
      h32[ct] = v;
      ushort hi = f2bf(v);
      st_sc2(&hbh[brow * 1024 + czc], hi);
      st_sc2(&hbl[brow * 1024 + czc], f2bf(v - bf2f(hi)));
    }
  } else {
#pragma unroll
    for (int ct = 0; ct < 2; ++ct) h32[ct] = h32g[brow * 1024 + cz0 + ct * 16];
  }
  tgt += 1; gbarf(flags, wgc, tgt);   // LDS staging + h init visibility

  const ushort* hhp = hbh + (size_t)(grp4 * 16 + lr) * 1024 + kbase + lkq * 8;
  const ushort* hlp = hbl + (size_t)(grp4 * 16 + lr) * 1024 + kbase + lkq * 8;
  const ushort* rhp = rhh + (size_t)(grp4 * 16 + lr) * 1024 + kbase + lkq * 8;
  const ushort* rlp = rhl + (size_t)(grp4 * 16 + lr) * 1024 + kbase + lkq * 8;
  const ushort* wzl0 = WzrL + (size_t)(wgc * 32 + lr) * 1024 + kbase + lkq * 8;
  const ushort* wzl1 = wzl0 + 16 * 1024;
  const ushort* wrl0 = WzrL + (size_t)(1024 + wgc * 32 + lr) * 1024 + kbase + lkq * 8;
  const ushort* wrl1 = wrl0 + 16 * 1024;
  const ushort* wgh0 = WgH + (size_t)(wgc * 32 + lr) * 1024 + kbase + lkq * 8;
  const ushort* wgh1 = wgh0 + 16 * 1024;
  const ushort* wgl0 = WgL + (size_t)(wgc * 32 + lr) * 1024 + kbase + lkq * 8;
  const ushort* wgl1 = wgl0 + 16 * 1024;

  for (int tl = 0; tl < TC; ++tl) {
    const size_t prow = (size_t)(brow * TC + tl) * 3072;
    // P prefetch (r16): retires under the h-load vmcnt(0)
    float pz[2], pr[2], pg[2];
#pragma unroll
    for (int ct = 0; ct < 2; ++ct) {
      int czc = cz0 + ct * 16;
      pz[ct] = P[prow + czc];
      pr[ct] = P[prow + 1024 + czc];
      pg[ct] = P[prow + 2048 + czc];
    }
    // ---- stage 1: r-matmul only; h fragments retained for stage 2's z ----
    s16x8 hh[8], hl[8];
    {
#pragma unroll
      for (int e = 0; e < 8; ++e) {
        hh[e] = ld_sc16(hhp + e * 32);
        hl[e] = ld_sc16(hlp + e * 32);
      }
      asm volatile("s_waitcnt vmcnt(0)" ::: "memory");
      __builtin_amdgcn_sched_barrier(0);
      f32x4 ar0 = {}, ar1 = {};
#pragma unroll
      for (int ks = 0; ks < 8; ++ks) {
        int kc = kbase + ks * 32 + lkq * 8;
        s16x8 wrA = *(const s16x8*)(&Wrh[lr][kc]);
        s16x8 wrB = *(const s16x8*)(&Wrh[16 + lr][kc]);
        s16x8 rlA = *(const s16x8*)(wrl0 + ks * 32);
        s16x8 rlB = *(const s16x8*)(wrl1 + ks * 32);
        ar0 = MFMA(hh[ks], wrA, ar0, 0, 0, 0);
        ar0 = MFMA(hl[ks], wrA, ar0, 0, 0, 0);
        ar0 = MFMA(hh[ks], rlA, ar0, 0, 0, 0);
        ar1 = MFMA(hh[ks], wrB, ar1, 0, 0, 0);
        ar1 = MFMA(hl[ks], wrB, ar1, 0, 0, 0);
        ar1 = MFMA(hh[ks], rlB, ar1, 0, 0, 0);
      }
#pragma unroll
      for (int i = 0; i < 4; ++i) {
        red[w][lane][i] = ar0[i];
        red[w][lane][4 + i] = ar1[i];
      }
      __syncthreads();
#pragma unroll
      for (int ct = 0; ct < 2; ++ct) {
        int czc = cz0 + ct * 16;
        float ars = red[0][lane][ct * 4 + w] + red[1][lane][ct * 4 + w] +
                    red[2][lane][ct * 4 + w] + red[3][lane][ct * 4 + w];
        float rv = sigm(pr[ct] + brc[ct] + ars);
        float p = rv * h32[ct];
        ushort ph = f2bf(p);
        st_sc2(&rhh[brow * 1024 + czc], ph);
        st_sc2(&rhl[brow * 1024 + czc], f2bf(p - bf2f(ph)));
      }
    }
    tgt += 1; gbarf(flags, wgc, tgt);
    // ---- stage 2: rh loads in flight while z-matmul runs on retained h regs ----
    {
      s16x8 rh8[8], rl8[8];
#pragma unroll
      for (int e = 0; e < 8; ++e) {
        rh8[e] = ld_sc16(rhp + e * 32);
        rl8[e] = ld_sc16(rlp + e * 32);
      }
      f32x4 az0 = {}, az1 = {};
#pragma unroll
      for (int ks = 0; ks < 8; ++ks) {
        int kc = kbase + ks * 32 + lkq * 8;
        s16x8 wzA = *(const s16x8*)(&Wzh[lr][kc]);
        s16x8 wzB = *(const s16x8*)(&Wzh[16 + lr][kc]);
        s16x8 zlA = *(const s16x8*)(wzl0 + ks * 32);
        s16x8 zlB = *(const s16x8*)(wzl1 + ks * 32);
        az0 = MFMA(hh[ks], wzA, az0, 0, 0, 0);
        az0 = MFMA(hl[ks], wzA, az0, 0, 0, 0);
        az0 = MFMA(hh[ks], zlA, az0, 0, 0, 0);
        az1 = MFMA(hh[ks], wzB, az1, 0, 0, 0);
        az1 = MFMA(hl[ks], wzB, az1, 0, 0, 0);
        az1 = MFMA(hh[ks], zlB, az1, 0, 0, 0);
      }
      asm volatile("s_waitcnt vmcnt(0)" ::: "memory");
      __builtin_amdgcn_sched_barrier(0);
      f32x4 ag0 = {}, ag1 = {};
#pragma unroll
      for (int ks = 0; ks < 8; ++ks) {
        s16x8 ghA = *(const s16x8*)(wgh0 + ks * 32);
        s16x8 ghB = *(const s16x8*)(wgh1 + ks * 32);
        s16x8 glA = *(const s16x8*)(wgl0 + ks * 32);
        s16x8 glB = *(const s16x8*)(wgl1 + ks * 32);
        ag0 = MFMA(rh8[ks], ghA, ag0, 0, 0, 0);
        ag0 = MFMA(rl8[ks], ghA, ag0, 0, 0, 0);
        ag0 = MFMA(rh8[ks], glA, ag0, 0, 0, 0);
        ag1 = MFMA(rh8[ks], ghB, ag1, 0, 0, 0);
        ag1 = MFMA(rl8[ks], ghB, ag1, 0, 0, 0);
        ag1 = MFMA(rh8[ks], glB, ag1, 0, 0, 0);
      }
#pragma unroll
      for (int i = 0; i < 4; ++i) {
        red[w][lane][i] = az0[i];      red[w][lane][4 + i] = az1[i];
        red[w][lane][8 + i] = ag0[i];  red[w][lane][12 + i] = ag1[i];
      }
      __syncthreads();
#pragma unroll
      for (int ct = 0; ct < 2; ++ct) {
        int czc = cz0 + ct * 16;
        float azs = red[0][lane][ct * 4 + w] + red[1][lane][ct * 4 + w] +
                    red[2][lane][ct * 4 + w] + red[3][lane][ct * 4 + w];
        float ags = red[0][lane][8 + ct * 4 + w] + red[1][lane][8 + ct * 4 + w] +
                    red[2][lane][8 + ct * 4 + w] + red[3][lane][8 + ct * 4 + w];
        float zvv = sigm(pz[ct] + bzc[ct] + azs);
        float g = tanh_(pg[ct] + bgc[ct] + ags);
        float hn = zvv * h32[ct] + (1.f - zvv) * g;
        h32[ct] = hn;
        ushort hi = f2bf(hn);
        ushort lo = f2bf(hn - bf2f(hi));
        st_sc2(&hbh[brow * 1024 + czc], hi);
        st_sc2(&hbl[brow * 1024 + czc], lo);
        size_t so = (size_t)(brow * TC + tl) * 1024 + czc;
        Sh[so] = hi; Sl[so] = lo;
        if (t0 + tl == 511) A.hidout[(size_t)(brow * 2 + layer) * 1024 + czc] = hn;
      }
    }
    tgt += 1; gbarf(flags, wgc, tgt);
  }
#pragma unroll
  for (int ct = 0; ct < 2; ++ct) h32g[brow * 1024 + cz0 + ct * 16] = h32[ct];
}

// ---------- workspace layout (bytes) ----------
static constexpr size_t OFF_WXT0H   = 0;
static constexpr size_t OFF_WXT0L   = OFF_WXT0H + 3072ull * 512 * 2;
static constexpr size_t OFF_WHZRT0H = OFF_WXT0L + 3072ull * 512 * 2;
static constexpr size_t OFF_WHZRT0L = OFF_WHZRT0H + 2048ull * 1024 * 2;
static constexpr size_t OFF_WHGT0H  = OFF_WHZRT0L + 2048ull * 1024 * 2;
static constexpr size_t OFF_WHGT0L  = OFF_WHGT0H + 1024ull * 1024 * 2;
static constexpr size_t OFF_WXT1H   = OFF_WHGT0L + 1024ull * 1024 * 2;
static constexpr size_t OFF_WXT1L   = OFF_WXT1H + 3072ull * 1024 * 2;
static constexpr size_t OFF_WHZRT1H = OFF_WXT1L + 3072ull * 1024 * 2;
static constexpr size_t OFF_WHZRT1L = OFF_WHZRT1H + 2048ull * 1024 * 2;
static constexpr size_t OFF_WHGT1H  = OFF_WHZRT1L + 2048ull * 1024 * 2;
static constexpr size_t OFF_WHGT1L  = OFF_WHGT1H + 1024ull * 1024 * 2;
static constexpr size_t OFF_WHYTH   = OFF_WHGT1L + 1024ull * 1024 * 2;
static constexpr size_t OFF_WHYTL   = OFF_WHYTH + 512ull * 1024 * 2;
static constexpr size_t OFF_P0      = OFF_WHYTL + 512ull * 1024 * 2;
static constexpr size_t OFF_S0H     = OFF_P0 + 1024ull * 3072 * 4;
static constexpr size_t OFF_S0L     = OFF_S0H + 1024ull * 1024 * 2;
static constexpr size_t OFF_S1H     = OFF_S0L + 1024ull * 1024 * 2;
static constexpr size_t OFF_S1L     = OFF_S1H + 1024ull * 1024 * 2;
static constexpr size_t OFF_HBH0    = OFF_S1L + 1024ull * 1024 * 2;
static constexpr size_t OFF_HBL0    = OFF_HBH0 + 64ull * 1024 * 2;
static constexpr size_t OFF_HBH1    = OFF_HBL0 + 64ull * 1024 * 2;
static constexpr size_t OFF_HBL1    = OFF_HBH1 + 64ull * 1024 * 2;
static constexpr size_t OFF_H320    = OFF_HBL1 + 64ull * 1024 * 2;
static constexpr size_t OFF_H321    = OFF_H320 + 64ull * 1024 * 4;
static constexpr size_t OFF_RHH0    = OFF_H321 + 64ull * 1024 * 4;
static constexpr size_t OFF_RHL0    = OFF_RHH0 + 64ull * 1024 * 2;
static constexpr size_t OFF_RHH1    = OFF_RHL0 + 64ull * 1024 * 2;
static constexpr size_t OFF_RHL1    = OFF_RHH1 + 64ull * 1024 * 2;
static constexpr size_t OFF_FLAGS   = OFF_RHL1 + 64ull * 1024 * 2;
static constexpr size_t OFF_END_SER = OFF_FLAGS + 4096;
static constexpr size_t OFF_P1      = OFF_END_SER;
static constexpr size_t OFF_END_PIPE = OFF_P1 + 1024ull * 3072 * 4;

extern "C" void kernel_launch(void* const* d_in, const int* in_sizes, int n_in,
                              void* d_out, int out_size, void* d_ws, size_t ws_size,
                              hipStream_t stream) {
  if (ws_size < OFF_END_SER) return;  // clean fail: zeros => absmax 12.875 signature
  const bool pipe = (ws_size >= OFF_END_PIPE);

  const float* x     = (const float*)d_in[0];
  const float* h0    = (const float*)d_in[1];
  const float* W_xz0 = (const float*)d_in[2];
  const float* W_hz0 = (const float*)d_in[3];
  const float* b_z0  = (const float*)d_in[4];
  const float* W_xr0 = (const float*)d_in[5];
  const float* W_hr0 = (const float*)d_in[6];
  const float* b_r0  = (const float*)d_in[7];
  const float* W_xg0 = (const float*)d_in[8];
  const float* W_hg0 = (const float*)d_in[9];
  const float* b_g0  = (const float*)d_in[10];
  const float* W_xz1 = (const float*)d_in[11];
  const float* W_hz1 = (const float*)d_in[12];
  const float* b_z1  = (const float*)d_in[13];
  const float* W_xr1 = (const float*)d_in[14];
  const float* W_hr1 = (const float*)d_in[15];
  const float* b_r1  = (const float*)d_in[16];
  const float* W_xg1 = (const float*)d_in[17];
  const float* W_hg1 = (const float*)d_in[18];
  const float* b_g1  = (const float*)d_in[19];
  const float* W_hy  = (const float*)d_in[20];
  const float* b_y   = (const float*)d_in[21];

  char* ws = (char*)d_ws;
  float* out_y   = (float*)d_out;
  float* out_hid = (float*)d_out + 16777216;
  unsigned* flags = (unsigned*)(ws + OFF_FLAGS);

  hipMemsetAsync(flags, 0, 4096, stream);

#define TRS(W, OFF_H, OFF_L, kbits, Nsrc, total) \
  tr_cvt_split<<<2048, 256, 0, stream>>>(W, (ushort*)(ws + OFF_H), (ushort*)(ws + OFF_L), kbits, Nsrc, total)
  TRS(W_xz0, OFF_WXT0H,                  OFF_WXT0L,                   9, 1024, 1024 * 512);
  TRS(W_xr0, OFF_WXT0H + 1024ull*512*2,  OFF_WXT0L + 1024ull*512*2,   9, 1024, 1024 * 512);
  TRS(W_xg0, OFF_WXT0H + 2048ull*512*2,  OFF_WXT0L + 2048ull*512*2,   9, 1024, 1024 * 512);
  TRS(W_hz0, OFF_WHZRT0H,                OFF_WHZRT0L,                10, 1024, 1024 * 1024);
  TRS(W_hr0, OFF_WHZRT0H + 1024ull*1024*2, OFF_WHZRT0L + 1024ull*1024*2, 10, 1024, 1024 * 1024);
  TRS(W_hg0, OFF_WHGT0H,                 OFF_WHGT0L,                 10, 1024, 1024 * 1024);
  TRS(W_xz1, OFF_WXT1H,                  OFF_WXT1L,                  10, 1024, 1024 * 1024);
  TRS(W_xr1, OFF_WXT1H + 1024ull*1024*2, OFF_WXT1L + 1024ull*1024*2, 10, 1024, 1024 * 1024);
  TRS(W_xg1, OFF_WXT1H + 2048ull*1024*2, OFF_WXT1L + 2048ull*1024*2, 10, 1024, 1024 * 1024);
  TRS(W_hz1, OFF_WHZRT1H,                OFF_WHZRT1L,                10, 1024, 1024 * 1024);
  TRS(W_hr1, OFF_WHZRT1H + 1024ull*1024*2, OFF_WHZRT1L + 1024ull*1024*2, 10, 1024, 1024 * 1024);
  TRS(W_hg1, OFF_WHGT1H,                 OFF_WHGT1L,                 10, 1024, 1024 * 1024);
  TRS(W_hy,  OFF_WHYTH,                  OFF_WHYTL,                  10, 512,  512 * 1024);
#undef TRS

  float*  P0  = (float*)(ws + OFF_P0);
  float*  P1  = pipe ? (float*)(ws + OFF_P1) : P0;
  ushort* S0h = (ushort*)(ws + OFF_S0H);
  ushort* S0l = (ushort*)(ws + OFF_S0L);
  ushort* S1h = (ushort*)(ws + OFF_S1H);
  ushort* S1l = (ushort*)(ws + OFF_S1L);
  ushort* Xh  = S1h;  // alias: X live split_x->proj0; S1 live scan->outproj
  ushort* Xl  = S1l;

  ScanArgs sa;
  sa.P0 = P0; sa.P1 = P1;
  sa.bz0 = b_z0; sa.br0 = b_r0; sa.bg0 = b_g0;
  sa.bz1 = b_z1; sa.br1 = b_r1; sa.bg1 = b_g1;
  sa.WzrH0 = (const ushort*)(ws + OFF_WHZRT0H); sa.WzrL0 = (const ushort*)(ws + OFF_WHZRT0L);
  sa.WgH0  = (const ushort*)(ws + OFF_WHGT0H);  sa.WgL0  = (const ushort*)(ws + OFF_WHGT0L);
  sa.WzrH1 = (const ushort*)(ws + OFF_WHZRT1H); sa.WzrL1 = (const ushort*)(ws + OFF_WHZRT1L);
  sa.WgH1  = (const ushort*)(ws + OFF_WHGT1H);  sa.WgL1  = (const ushort*)(ws + OFF_WHGT1L);
  sa.h0 = h0;
  sa.h32g0 = (float*)(ws + OFF_H320); sa.h32g1 = (float*)(ws + OFF_H321);
  sa.hbh0 = (ushort*)(ws + OFF_HBH0); sa.hbl0 = (ushort*)(ws + OFF_HBL0);
  sa.hbh1 = (ushort*)(ws + OFF_HBH1); sa.hbl1 = (ushort*)(ws + OFF_HBL1);
  sa.rhh0 = (ushort*)(ws + OFF_RHH0); sa.rhl0 = (ushort*)(ws + OFF_RHL0);
  sa.rhh1 = (ushort*)(ws + OFF_RHH1); sa.rhl1 = (ushort*)(ws + OFF_RHL1);
  sa.S0h = S0h; sa.S0l = S0l; sa.S1h = S1h; sa.S1l = S1l;
  sa.hidout = out_hid;
  sa.flags = flags;

  const ushort* WXT0H = (const ushort*)(ws + OFF_WXT0H);
  const ushort* WXT0L = (const ushort*)(ws + OFF_WXT0L);
  const ushort* WXT1H = (const ushort*)(ws + OFF_WXT1H);
  const ushort* WXT1L = (const ushort*)(ws + OFF_WXT1L);
  const ushort* WHYH  = (const ushort*)(ws + OFF_WHYTH);
  const ushort* WHYL  = (const ushort*)(ws + OFF_WHYTL);

  unsigned launch_idx = 0;
  if (pipe) {
    for (int lc = 0; lc <= 32; ++lc) {
      int c0 = (lc < 32) ? lc : -1;
      int c1 = lc - 1;
      if (c0 >= 0) {
        split_x_chunk<<<1024, 256, 0, stream>>>(x, Xh, Xl, c0 * TC);
        gemm3q<0><<<dim3(8, 24), 256, 0, stream>>>(Xh, Xl, WXT0H, WXT0L,
                                                   P0, nullptr, 1024, 3072, 512, 0);
      }
      if (c1 >= 0)
        gemm3q<0><<<dim3(8, 24), 256, 0, stream>>>(S0h, S0l, WXT1H, WXT1L,
                                                   P1, nullptr, 1024, 3072, 1024, 0);
      sa.c0 = c0; sa.c1 = c1; sa.bar_base = launch_idx * 33; ++launch_idx;
      gru_scan2<<<256, 256, 0, stream>>>(sa);
      if (c1 >= 0)
        gemm3q<1><<<dim3(8, 4), 256, 0, stream>>>(S1h, S1l, WHYH, WHYL,
                                                  out_y, b_y, 1024, 512, 1024, c1 * TC);
    }
  } else {
    for (int c = 0; c < 32; ++c) {
      split_x_chunk<<<1024, 256, 0, stream>>>(x, Xh, Xl, c * TC);
      gemm3q<0><<<dim3(8, 24), 256, 0, stream>>>(Xh, Xl, WXT0H, WXT0L,
                                                 P0, nullptr, 1024, 3072, 512, 0);
      sa.c0 = c; sa.c1 = -1; sa.bar_base = launch_idx * 33; ++launch_idx;
      gru_scan2<<<256, 256, 0, stream>>>(sa);
      gemm3q<0><<<dim3(8, 24), 256, 0, stream>>>(S0h, S0l, WXT1H, WXT1L,
                                                 P0, nullptr, 1024, 3072, 1024, 0);
      sa.c0 = -1; sa.c1 = c; sa.bar_base = launch_idx * 33; ++launch_idx;
      gru_scan2<<<256, 256, 0, stream>>>(sa);
      gemm3q<1><<<dim3(8, 4), 256, 0, stream>>>(S1h, S1l, WHYH, WHYL,
                                                out_y, b_y, 1024, 512, 1024, c * TC);
    }
  }
}